// Round 2
// baseline (310.352 us; speedup 1.0000x reference)
//
#include <hip/hip_runtime.h>

#define HH 299
#define WW 299
#define BORDER 3
#define NCHUNK 8

__global__ __launch_bounds__(256) void crop_resize_kernel(
    const float* __restrict__ x,   // (S, 3, H, W)
    const int*   __restrict__ f,   // (S, G, 4)
    float*       __restrict__ out, // (S, G, 3, H, W)
    int S, int G)
{
    __shared__ int   s_gy0[WW];
    __shared__ int   s_gy1[WW];
    __shared__ float s_fy[WW];

    int blk   = blockIdx.x;
    int chunk = blk % NCHUNK;
    int sg    = blk / NCHUNK;
    int gi    = sg % G;
    int si    = sg / G;

    const int* box = f + ((size_t)si * G + gi) * 4;
    int tlx = max(box[0] - BORDER, 0);
    int tly = max(box[1] - BORDER, 0);
    int brx = min(box[2] + BORDER, HH - 1);
    int bry = min(box[3] + BORDER, WW - 1);
    int hc = brx - tlx;   // extent along output H axis
    int wc = bry - tly;   // extent along output W axis

    // y-axis (column) coords: identical for every row of this crop -> LDS once
    float wf = (float)wc;
    for (int j = threadIdx.x; j < WW; j += 256) {
        float sy = ((j + 0.5f) * wf) / (float)WW - 0.5f;
        sy = fminf(fmaxf(sy, 0.0f), wf - 1.0f);
        int yi0 = (int)floorf(sy);
        yi0 = min(yi0, wc - 1);
        int yi1 = min(yi0 + 1, wc - 1);
        s_fy[j]  = sy - (float)yi0;
        s_gy0[j] = tly + yi0;
        s_gy1[j] = tly + yi1;
    }
    __syncthreads();

    int r0 = (chunk * HH) / NCHUNK;
    int r1 = ((chunk + 1) * HH) / NCHUNK;

    const float* img   = x   + (size_t)si * 3 * HH * WW;
    float*       obase = out + ((size_t)si * G + gi) * 3 * HH * WW;

    float hf = (float)hc;
    for (int row = r0; row < r1; ++row) {
        float sx = ((row + 0.5f) * hf) / (float)HH - 0.5f;
        sx = fminf(fmaxf(sx, 0.0f), hf - 1.0f);
        int xi0 = (int)floorf(sx);
        xi0 = min(xi0, hc - 1);
        int xi1 = min(xi0 + 1, hc - 1);
        float fx   = sx - (float)xi0;
        float omfx = 1.0f - fx;
        int gx0 = tlx + xi0;
        int gx1 = tlx + xi1;

        const float* r0p = img + (size_t)gx0 * WW;  // channel-0 row gx0
        const float* r1p = img + (size_t)gx1 * WW;  // channel-0 row gx1
        float* orow = obase + (size_t)row * WW;

        for (int j = threadIdx.x; j < WW; j += 256) {
            int   gy0 = s_gy0[j];
            int   gy1 = s_gy1[j];
            float fy  = s_fy[j];
            float omfy = 1.0f - fy;
            #pragma unroll
            for (int c = 0; c < 3; ++c) {
                const float* p0 = r0p + (size_t)c * HH * WW;
                const float* p1 = r1p + (size_t)c * HH * WW;
                float v00 = p0[gy0], v01 = p0[gy1];
                float v10 = p1[gy0], v11 = p1[gy1];
                float top = fmaf(v00, omfy, v01 * fy);
                float bot = fmaf(v10, omfy, v11 * fy);
                float val = fmaf(top, omfx, bot * fx);
                __builtin_nontemporal_store(val, orow + (size_t)c * HH * WW + j);
            }
        }
    }
}

extern "C" void kernel_launch(void* const* d_in, const int* in_sizes, int n_in,
                              void* d_out, int out_size, void* d_ws, size_t ws_size,
                              hipStream_t stream) {
    const float* x = (const float*)d_in[0];
    const int*   f = (const int*)d_in[1];
    float* out = (float*)d_out;

    int S = in_sizes[0] / (3 * HH * WW);   // 32
    int G = in_sizes[1] / (S * 4);         // 16

    dim3 grid((unsigned)(S * G * NCHUNK)); // 4096 blocks
    dim3 block(256);
    crop_resize_kernel<<<grid, block, 0, stream>>>(x, f, out, S, G);
}